// Round 11
// baseline (252.211 us; speedup 1.0000x reference)
//
#include <hip/hip_runtime.h>

#define NN 50000      // nodes (fits in 16 bits: col packed as ushort)
#define NE 800000     // edges
#define DF 64         // features
#define MM 11         // (a,b) tuples
#define OUT_K 4       // DEPTH+1 output planes
#define PAD 16        // row slabs padded to multiple of PAD
// quad-max padding: 4 rows padded to common length; bound 4 * sum(per-row pad)
#define SLAB_CAP (4 * (NE + (PAD - 1) * NN) + 256)
#define NQ (NN / 4)   // 12500 quads

typedef unsigned int uivec4 __attribute__((ext_vector_type(4)));

__device__ __forceinline__ float bf2f(unsigned short u) {
    union { unsigned int i; float f; } v; v.i = ((unsigned int)u) << 16; return v.f;
}
__device__ __forceinline__ unsigned short f2bf(float f) {
    union { float f; unsigned int i; } v; v.f = f;
    unsigned int u = v.i + 0x7FFFu + ((v.i >> 16) & 1u);
    return (unsigned short)(u >> 16);
}

// ---------------- CSR build ----------------

// deg AND per-edge rank within its row (the atomic's old value — free sort key)
__global__ void k_deg(const int* __restrict__ row, int* __restrict__ deg,
                      unsigned short* __restrict__ rank) {
    int e = blockIdx.x * blockDim.x + threadIdx.x;
    if (e < NE) {
        int r = row[e];
        rank[e] = (unsigned short)atomicAdd(&deg[r], 1);
    }
}

// slab alloc: QUAD-max padding — rows 4k..4k+3 share a common padded length
// mq = max(pad16(d_j)); rowstart[4k+q] = quadbase + q*mq (mq = rowstart diff).
// Two-level scan, one atomic per 1024-block. Emits dinv, sqd. gamma on wave 0.
__global__ __launch_bounds__(1024) void k_alloc(
        const int* __restrict__ deg, int* __restrict__ counter,
        int* __restrict__ rowstart, float* __restrict__ dinv,
        float* __restrict__ sqd,
        const float* __restrict__ alphas, const float* __restrict__ w,
        const float* __restrict__ a_arr, const float* __restrict__ b_arr,
        float* __restrict__ gamma) {
    __shared__ int wtot[16];
    __shared__ int blockbase;
    int i = blockIdx.x * 1024 + threadIdx.x;
    int wave = threadIdx.x >> 6;
    int lane = threadIdx.x & 63;

    int d = (i < NN) ? deg[i] : 0;
    int dp = (d + PAD - 1) & ~(PAD - 1);
    dp = max(dp, __shfl_xor(dp, 1, 64));
    dp = max(dp, __shfl_xor(dp, 2, 64));  // mq: uniform across the 4-lane quad
    int mq = dp;
    int v = mq;                           // each node contributes mq (4 -> 4*mq)
    #pragma unroll
    for (int off = 1; off < 64; off <<= 1) {
        int t = __shfl_up(v, off, 64);
        if (lane >= off) v += t;
    }
    if (lane == 63) wtot[wave] = v;
    __syncthreads();
    if (wave == 0) {
        int t = (lane < 16) ? wtot[lane] : 0;
        #pragma unroll
        for (int off = 1; off < 16; off <<= 1) {
            int u = __shfl_up(t, off, 64);
            if (lane >= off) t += u;
        }
        if (lane == 15) blockbase = atomicAdd(counter, t);  // block total
        if (lane < 16) wtot[lane] = t;                      // inclusive scan
    }
    __syncthreads();
    int base = blockbase + (wave ? wtot[wave - 1] : 0);
    if (i < NN) {
        rowstart[i] = base + v - mq;      // quadbase + (i&3)*mq
        float dc = (float)(d == 0 ? 1 : d);
        float s = sqrtf(dc);
        sqd[i] = s;
        dinv[i] = 1.0f / s;
    }

    // gamma[k][j] = sum_m w_m c_{k,m,j}: one m per lane, shuffle-reduce.
    if (blockIdx.x == 0 && wave == 0) {
        float g[OUT_K][OUT_K];
        #pragma unroll
        for (int k = 0; k < OUT_K; ++k)
            #pragma unroll
            for (int j = 0; j < OUT_K; ++j) g[k][j] = 0.f;
        if (lane < MM) {
            int m = lane;
            float a = a_arr[m], b = b_arr[m], wm = w[m];
            float c[OUT_K][OUT_K];
            #pragma unroll
            for (int k = 0; k < OUT_K; ++k)
                #pragma unroll
                for (int j = 0; j < OUT_K; ++j) c[k][j] = 0.f;
            c[0][0] = 1.f;
            float al0 = alphas[m];
            c[1][0] = al0 * 0.5f * (a - b);        // l=-1, r=1
            c[1][1] = al0 * 0.5f * (a + b + 2.f);
            #pragma unroll
            for (int L = 2; L <= 3; ++L) {
                float Lf = (float)L;
                float alL = alphas[(L - 1) * MM + m];
                float alm = alphas[(L - 2) * MM + m];
                float ab = a + b;
                float t2L = 2.f * Lf + ab;
                float coef_l = 2.f * Lf * (Lf + ab) * (t2L - 2.f);
                float inv = 1.f / coef_l;
                float t1 = alL * ((t2L - 1.f) * t2L * (t2L - 2.f)) * inv;
                float t2 = alL * ((t2L - 1.f) * (a * a - b * b)) * inv;
                float t3 = alL * alm * (2.f * (Lf - 1.f + a) * (Lf - 1.f + b) * t2L) * inv;
                #pragma unroll
                for (int j = 0; j < OUT_K; ++j) {
                    float ps = (j > 0) ? c[L - 1][j - 1] : 0.f;
                    c[L][j] = t1 * ps - t2 * c[L - 1][j] - t3 * c[L - 2][j];
                }
            }
            #pragma unroll
            for (int k = 0; k < OUT_K; ++k)
                #pragma unroll
                for (int j = 0; j < OUT_K; ++j) g[k][j] = wm * c[k][j];
        }
        #pragma unroll
        for (int k = 0; k < OUT_K; ++k)
            #pragma unroll
            for (int j = 0; j < OUT_K; ++j) {
                float s = g[k][j];
                #pragma unroll
                for (int off = 32; off >= 1; off >>= 1) s += __shfl_down(s, off, 64);
                if (lane == 0) gamma[k * OUT_K + j] = s;
            }
    }
}

// fill (atomic-free: pos = rowstart + precomputed rank) + bf16 cast of the
// dinv-prescaled FULL gather table xs0 = dinv[node]*x, layout [NN][64].
// Record: low16 = col, high16 = bf16(ea).
__global__ void k_fill_cast(const int* __restrict__ row, const int* __restrict__ col,
                            const float* __restrict__ ea, const float* __restrict__ dinv,
                            const int* __restrict__ rowstart,
                            const unsigned short* __restrict__ rank,
                            unsigned int* __restrict__ ecv,
                            const float* __restrict__ x, unsigned short* __restrict__ xb) {
    int t = blockIdx.x * blockDim.x + threadIdx.x;
    if (t < NE) {
        int r = row[t], c = col[t];
        int pos = rowstart[r] + (int)rank[t];
        ecv[pos] = (unsigned int)(unsigned short)c | ((unsigned int)f2bf(ea[t]) << 16);
    } else {
        int j = t - NE;
        if (j < (NN * DF) / 8) {
            float dv = dinv[j >> 3];               // 8 threads share a node
            const float4* xf = (const float4*)x;
            float4 f0 = xf[2 * j];
            float4 f1 = xf[2 * j + 1];
            uint4 o;
            o.x = (unsigned int)f2bf(dv * f0.x) | ((unsigned int)f2bf(dv * f0.y) << 16);
            o.y = (unsigned int)f2bf(dv * f0.z) | ((unsigned int)f2bf(dv * f0.w) << 16);
            o.z = (unsigned int)f2bf(dv * f1.x) | ((unsigned int)f2bf(dv * f1.y) << 16);
            o.w = (unsigned int)f2bf(dv * f1.z) | ((unsigned int)f2bf(dv * f1.w) << 16);
            ((uint4*)xb)[j] = o;
        }
    }
}

// ---- SpMM: wave = row QUAD; 16 lanes/row, each lane = 4 feats (uint2 gather) ----
// 16 addresses per edge-record instead of 32 (TA address-throughput is the bound);
// 16 lanes x 8B = 128B contiguous per record — same bytes/lines as before.
// Each record decoded ONCE; ecv streamed ONCE; full [NN][64] table.
__device__ __forceinline__ void spmm_quad(const unsigned int* __restrict__ ecv,
                                          int s, int mq,
                                          const unsigned short* __restrict__ xin,
                                          int t4, float acc[4]) {
    for (int i = 0; i < mq; i += PAD) {
        const uivec4* p = (const uivec4*)(ecv + s + i);
        uivec4 q0 = __builtin_nontemporal_load(p);
        uivec4 q1 = __builtin_nontemporal_load(p + 1);
        uivec4 q2 = __builtin_nontemporal_load(p + 2);
        uivec4 q3 = __builtin_nontemporal_load(p + 3);
        unsigned int rec[PAD] = {q0.x, q0.y, q0.z, q0.w, q1.x, q1.y, q1.z, q1.w,
                                 q2.x, q2.y, q2.z, q2.w, q3.x, q3.y, q3.z, q3.w};
        uint2 g[PAD];
        #pragma unroll
        for (int j = 0; j < PAD; ++j)
            g[j] = *(const uint2*)(xin + (rec[j] & 0xFFFFu) * DF + t4);
        #pragma unroll
        for (int j = 0; j < PAD; ++j) {
            float wf = __uint_as_float(rec[j] & 0xFFFF0000u);  // bf16 weight (ea)
            acc[0] = fmaf(wf, __uint_as_float(g[j].x << 16), acc[0]);
            acc[1] = fmaf(wf, __uint_as_float(g[j].x & 0xFFFF0000u), acc[1]);
            acc[2] = fmaf(wf, __uint_as_float(g[j].y << 16), acc[2]);
            acc[3] = fmaf(wf, __uint_as_float(g[j].y & 0xFFFF0000u), acc[3]);
        }
    }
}

// Stores the NEXT layer's prescaled table: xs_next = dinv[r]*y = dinv[r]^2*raw.
__global__ __launch_bounds__(256, 8) void k_spmm(
    const int* __restrict__ rowstart, const float* __restrict__ dinv,
    const unsigned int* __restrict__ ecv, const unsigned short* __restrict__ xin,
    unsigned short* __restrict__ bout) {
    int quad = (blockIdx.x * blockDim.x + threadIdx.x) >> 6;
    if (quad >= NQ) return;
    int lane = threadIdx.x & 63;
    int q = lane >> 4, t4 = (lane & 15) * 4;
    int r = 4 * quad + q;
    int s = rowstart[r];
    int mq = __shfl(s, 16, 64) - __shfl(s, 0, 64);   // quad-uniform slab length
    float acc[4] = {0.f, 0.f, 0.f, 0.f};
    spmm_quad(ecv, s, mq, xin, t4, acc);
    float dv = dinv[r];
    float dv2 = dv * dv;                 // next prescaled table = dinv^2 * raw
    uint2 o;
    o.x = (unsigned int)f2bf(acc[0] * dv2) | ((unsigned int)f2bf(acc[1] * dv2) << 16);
    o.y = (unsigned int)f2bf(acc[2] * dv2) | ((unsigned int)f2bf(acc[3] * dv2) << 16);
    *(uint2*)(bout + r * DF + t4) = o;
}

// third SpMM + fused output combine (y3 never hits memory);
// tables are prescaled by dinv[r], so y_k = table_k[r] * sqd[r].
__global__ __launch_bounds__(256, 8) void k_spmm_comb(
    const int* __restrict__ rowstart, const float* __restrict__ dinv,
    const float* __restrict__ sqd,
    const unsigned int* __restrict__ ecv, const unsigned short* __restrict__ xin,
    const float* __restrict__ x, const unsigned short* __restrict__ xb1,
    const float* __restrict__ gamma, float* __restrict__ out) {
    int quad = (blockIdx.x * blockDim.x + threadIdx.x) >> 6;
    if (quad >= NQ) return;
    int lane = threadIdx.x & 63;
    int q = lane >> 4, t4 = (lane & 15) * 4;
    int r = 4 * quad + q;
    int s = rowstart[r];
    int mq = __shfl(s, 16, 64) - __shfl(s, 0, 64);
    float acc[4] = {0.f, 0.f, 0.f, 0.f};
    spmm_quad(ecv, s, mq, xin, t4, acc);
    float dv = dinv[r];
    float v3[4];
    #pragma unroll
    for (int t = 0; t < 4; ++t) v3[t] = acc[t] * dv;   // y3 = dinv*raw
    float sq = sqd[r];
    int base = r * DF + t4;
    float4 v0 = *(const float4*)(x + base);
    uint2 u1 = *(const uint2*)(xb1 + base);
    uint2 u2 = *(const uint2*)(xin + base);            // xin == xs2 table
    float v1[4] = {__uint_as_float(u1.x << 16) * sq,
                   __uint_as_float(u1.x & 0xFFFF0000u) * sq,
                   __uint_as_float(u1.y << 16) * sq,
                   __uint_as_float(u1.y & 0xFFFF0000u) * sq};
    float v2[4] = {__uint_as_float(u2.x << 16) * sq,
                   __uint_as_float(u2.x & 0xFFFF0000u) * sq,
                   __uint_as_float(u2.y << 16) * sq,
                   __uint_as_float(u2.y & 0xFFFF0000u) * sq};
    float vz[4] = {v0.x, v0.y, v0.z, v0.w};
    float gm[OUT_K * OUT_K];
    #pragma unroll
    for (int t = 0; t < OUT_K * OUT_K; ++t) gm[t] = gamma[t];
    #pragma unroll
    for (int k = 0; k < OUT_K; ++k) {
        float4 o;
        float* op = (float*)&o;
        #pragma unroll
        for (int t = 0; t < 4; ++t)
            op[t] = gm[k * OUT_K + 0] * vz[t] + gm[k * OUT_K + 1] * v1[t] +
                    gm[k * OUT_K + 2] * v2[t] + gm[k * OUT_K + 3] * v3[t];
        *(float4*)(out + (r * OUT_K + k) * DF + t4) = o;
    }
}

// ---------------- launch ----------------

extern "C" void kernel_launch(void* const* d_in, const int* in_sizes, int n_in,
                              void* d_out, int out_size, void* d_ws, size_t ws_size,
                              hipStream_t stream) {
    const float* x      = (const float*)d_in[0];
    const int*   ei     = (const int*)d_in[1];
    const float* ea     = (const float*)d_in[2];
    const float* alphas = (const float*)d_in[3];
    const float* w      = (const float*)d_in[4];
    const float* a_arr  = (const float*)d_in[5];
    const float* b_arr  = (const float*)d_in[6];
    float* out = (float*)d_out;
    const int* row = ei;
    const int* col = ei + NE;

    char* ws = (char*)d_ws;
    size_t off = 0;
    auto alloc = [&](size_t bytes) {
        void* p = ws + off;
        off = (off + bytes + 255) & ~(size_t)255;
        return p;
    };
    // deg/counter then ecv are contiguous so ONE memset zeroes all
    // (ecv pad slots must be 0: col=0, bf16 weight=+0).
    int* deg      = (int*)alloc((size_t)(NN + 1) * sizeof(int));
    int* counter  = deg + NN;
    unsigned int* ecv = (unsigned int*)alloc((size_t)SLAB_CAP * sizeof(unsigned int));
    size_t zero_end = off;
    int* rowstart = (int*)alloc((size_t)NN * sizeof(int));
    float* dinv   = (float*)alloc((size_t)NN * sizeof(float));
    float* sqd    = (float*)alloc((size_t)NN * sizeof(float));
    unsigned short* rank = (unsigned short*)alloc((size_t)NE * sizeof(unsigned short));
    unsigned short* xb0 = (unsigned short*)alloc((size_t)NN * DF * sizeof(unsigned short));
    unsigned short* xb1 = (unsigned short*)alloc((size_t)NN * DF * sizeof(unsigned short));
    unsigned short* xb2 = (unsigned short*)alloc((size_t)NN * DF * sizeof(unsigned short));
    float* gamma = (float*)alloc((size_t)OUT_K * OUT_K * sizeof(float));

    (void)hipMemsetAsync(deg, 0, zero_end, stream);

    k_deg<<<(NE + 255) / 256, 256, 0, stream>>>(row, deg, rank);
    k_alloc<<<(NN + 1023) / 1024, 1024, 0, stream>>>(deg, counter, rowstart, dinv, sqd,
                                                     alphas, w, a_arr, b_arr, gamma);
    k_fill_cast<<<(NE + (NN * DF) / 8 + 255) / 256, 256, 0, stream>>>(
        row, col, ea, dinv, rowstart, rank, ecv, x, xb0);

    int blocks = (NQ + 3) / 4;  // one wave per row QUAD, 4 quads per block
    k_spmm<<<blocks, 256, 0, stream>>>(rowstart, dinv, ecv, xb0, xb1);
    k_spmm<<<blocks, 256, 0, stream>>>(rowstart, dinv, ecv, xb1, xb2);
    k_spmm_comb<<<blocks, 256, 0, stream>>>(rowstart, dinv, sqd, ecv, xb2, x, xb1,
                                            gamma, out);
}

// Round 12
// 207.119 us; speedup vs baseline: 1.2177x; 1.2177x over previous
//
#include <hip/hip_runtime.h>
#include <hip/hip_fp16.h>

#define NN 50000      // nodes (fits in 16 bits: col packed as ushort)
#define NE 800000     // edges
#define DF 64         // features
#define MM 11         // (a,b) tuples
#define OUT_K 4       // DEPTH+1 output planes
#define PAD 16        // row slabs padded to multiple of PAD (16: best-measured SpMM batch)
// pair-max padding: each row pair padded to 2*max -> bounded by 2*sum
#define SLAB_CAP (2 * (NE + (PAD - 1) * NN) + 128)

typedef unsigned int uivec4 __attribute__((ext_vector_type(4)));

__device__ __forceinline__ float bf2f(unsigned short u) {
    union { unsigned int i; float f; } v; v.i = ((unsigned int)u) << 16; return v.f;
}
__device__ __forceinline__ unsigned short f2bf(float f) {
    union { float f; unsigned int i; } v; v.f = f;
    unsigned int u = v.i + 0x7FFFu + ((v.i >> 16) & 1u);
    return (unsigned short)(u >> 16);
}

// ---------------- CSR build ----------------

// deg AND per-edge rank within its row (the atomic's old value — free sort key)
__global__ void k_deg(const int* __restrict__ row, int* __restrict__ deg,
                      unsigned short* __restrict__ rank) {
    int e = blockIdx.x * blockDim.x + threadIdx.x;
    if (e < NE) {
        int r = row[e];
        rank[e] = (unsigned short)atomicAdd(&deg[r], 1);
    }
}

// slab alloc: 1024-thread blocks, two-level (wave shfl + LDS) scan,
// ONE atomic per block. Row pairs (2i,2i+1) padded to a COMMON length
// m = max(pad(deg_2i), pad(deg_2i+1)); m recoverable as rowstart diff.
// Emits dinv = deg^-1/2 and sqd = deg^+1/2 (deg clamped >=1).
// gamma parallelized over m on wave 0 of block 0.
__global__ __launch_bounds__(1024) void k_alloc(
        const int* __restrict__ deg, int* __restrict__ counter,
        int* __restrict__ rowstart, float* __restrict__ dinv,
        float* __restrict__ sqd,
        const float* __restrict__ alphas, const float* __restrict__ w,
        const float* __restrict__ a_arr, const float* __restrict__ b_arr,
        float* __restrict__ gamma) {
    __shared__ int wtot[16];
    __shared__ int blockbase;
    int i = blockIdx.x * 1024 + threadIdx.x;
    int wave = threadIdx.x >> 6;
    int lane = threadIdx.x & 63;

    int d = (i < NN) ? deg[i] : 0;
    int dp = (d + PAD - 1) & ~(PAD - 1);
    int dpo = __shfl_xor(dp, 1, 64);      // pair partner's padded length
    int mp = max(dp, dpo);                // common pair length
    int v = mp;
    #pragma unroll
    for (int off = 1; off < 64; off <<= 1) {
        int t = __shfl_up(v, off, 64);
        if (lane >= off) v += t;
    }
    if (lane == 63) wtot[wave] = v;
    __syncthreads();
    if (wave == 0) {
        int t = (lane < 16) ? wtot[lane] : 0;
        #pragma unroll
        for (int off = 1; off < 16; off <<= 1) {
            int u = __shfl_up(t, off, 64);
            if (lane >= off) t += u;
        }
        if (lane == 15) blockbase = atomicAdd(counter, t);  // block total
        if (lane < 16) wtot[lane] = t;                      // inclusive scan
    }
    __syncthreads();
    int base = blockbase + (wave ? wtot[wave - 1] : 0);
    if (i < NN) {
        rowstart[i] = base + v - mp;      // even row: pair base; odd: base+m
        float dc = (float)(d == 0 ? 1 : d);
        float s = sqrtf(dc);
        sqd[i] = s;
        dinv[i] = 1.0f / s;
    }

    // gamma[k][j] = sum_m w_m c_{k,m,j}: one m per lane, shuffle-reduce.
    if (blockIdx.x == 0 && wave == 0) {
        float g[OUT_K][OUT_K];
        #pragma unroll
        for (int k = 0; k < OUT_K; ++k)
            #pragma unroll
            for (int j = 0; j < OUT_K; ++j) g[k][j] = 0.f;
        if (lane < MM) {
            int m = lane;
            float a = a_arr[m], b = b_arr[m], wm = w[m];
            float c[OUT_K][OUT_K];
            #pragma unroll
            for (int k = 0; k < OUT_K; ++k)
                #pragma unroll
                for (int j = 0; j < OUT_K; ++j) c[k][j] = 0.f;
            c[0][0] = 1.f;
            float al0 = alphas[m];
            c[1][0] = al0 * 0.5f * (a - b);        // l=-1, r=1
            c[1][1] = al0 * 0.5f * (a + b + 2.f);
            #pragma unroll
            for (int L = 2; L <= 3; ++L) {
                float Lf = (float)L;
                float alL = alphas[(L - 1) * MM + m];
                float alm = alphas[(L - 2) * MM + m];
                float ab = a + b;
                float t2L = 2.f * Lf + ab;
                float coef_l = 2.f * Lf * (Lf + ab) * (t2L - 2.f);
                float inv = 1.f / coef_l;
                float t1 = alL * ((t2L - 1.f) * t2L * (t2L - 2.f)) * inv;
                float t2 = alL * ((t2L - 1.f) * (a * a - b * b)) * inv;
                float t3 = alL * alm * (2.f * (Lf - 1.f + a) * (Lf - 1.f + b) * t2L) * inv;
                #pragma unroll
                for (int j = 0; j < OUT_K; ++j) {
                    float ps = (j > 0) ? c[L - 1][j - 1] : 0.f;
                    c[L][j] = t1 * ps - t2 * c[L - 1][j] - t3 * c[L - 2][j];
                }
            }
            #pragma unroll
            for (int k = 0; k < OUT_K; ++k)
                #pragma unroll
                for (int j = 0; j < OUT_K; ++j) g[k][j] = wm * c[k][j];
        }
        #pragma unroll
        for (int k = 0; k < OUT_K; ++k)
            #pragma unroll
            for (int j = 0; j < OUT_K; ++j) {
                float s = g[k][j];
                #pragma unroll
                for (int off = 32; off >= 1; off >>= 1) s += __shfl_down(s, off, 64);
                if (lane == 0) gamma[k * OUT_K + j] = s;
            }
    }
}

// fill (atomic-free: pos = rowstart + precomputed rank) + bf16 cast of the
// dinv-prescaled gather table xs0 = dinv[node]*x.
// Record: low16 = col, high16 = bf16(ea) ONLY — no per-edge dinv[col] gather;
// dinv[col] lives in the table, dinv[row] applied at SpMM output.
__global__ void k_fill_cast(const int* __restrict__ row, const int* __restrict__ col,
                            const float* __restrict__ ea, const float* __restrict__ dinv,
                            const int* __restrict__ rowstart,
                            const unsigned short* __restrict__ rank,
                            unsigned int* __restrict__ ecv,
                            const float* __restrict__ x, unsigned short* __restrict__ xb) {
    int t = blockIdx.x * blockDim.x + threadIdx.x;
    if (t < NE) {
        int r = row[t], c = col[t];
        int pos = rowstart[r] + (int)rank[t];
        ecv[pos] = (unsigned int)(unsigned short)c | ((unsigned int)f2bf(ea[t]) << 16);
    } else {
        int j = t - NE;
        if (j < (NN * DF) / 8) {
            float dv = dinv[j >> 3];               // 8 threads share a node
            const float4* xf = (const float4*)x;
            float4 f0 = xf[2 * j];
            float4 f1 = xf[2 * j + 1];
            uint4 o;
            o.x = (unsigned int)f2bf(dv * f0.x) | ((unsigned int)f2bf(dv * f0.y) << 16);
            o.y = (unsigned int)f2bf(dv * f0.z) | ((unsigned int)f2bf(dv * f0.w) << 16);
            o.z = (unsigned int)f2bf(dv * f1.x) | ((unsigned int)f2bf(dv * f1.y) << 16);
            o.w = (unsigned int)f2bf(dv * f1.z) | ((unsigned int)f2bf(dv * f1.w) << 16);
            ((uint4*)xb)[j] = o;
        }
    }
}

// ------ SpMM: wave = row PAIR; lanes 0-31 row 2w, lanes 32-63 row 2w+1 ------
// Each lane covers 2 features (one uint gather = 2 bf16). Table is
// dinv-prescaled, so raw = sum(ea * xs[col]); y = dinv[row]*raw.
__device__ __forceinline__ void spmm_pair(const unsigned int* __restrict__ ecv,
                                          int s, int m,
                                          const unsigned short* __restrict__ xin,
                                          int fp, float& a0, float& a1) {
    for (int i = 0; i < m; i += PAD) {
        const uivec4* p = (const uivec4*)(ecv + s + i);
        uivec4 q0 = __builtin_nontemporal_load(p);
        uivec4 q1 = __builtin_nontemporal_load(p + 1);
        uivec4 q2 = __builtin_nontemporal_load(p + 2);
        uivec4 q3 = __builtin_nontemporal_load(p + 3);
        unsigned int rec[PAD] = {q0.x, q0.y, q0.z, q0.w, q1.x, q1.y, q1.z, q1.w,
                                 q2.x, q2.y, q2.z, q2.w, q3.x, q3.y, q3.z, q3.w};
        unsigned int g[PAD];
        #pragma unroll
        for (int j = 0; j < PAD; ++j)
            g[j] = *(const unsigned int*)(xin + (rec[j] & 0xFFFFu) * DF + 2 * fp);
        #pragma unroll
        for (int j = 0; j < PAD; ++j) {
            float wf = __uint_as_float(rec[j] & 0xFFFF0000u);  // bf16 weight (ea)
            a0 = fmaf(wf, __uint_as_float(g[j] << 16), a0);
            a1 = fmaf(wf, __uint_as_float(g[j] & 0xFFFF0000u), a1);
        }
    }
}

// Stores the NEXT layer's prescaled table: xs_next = dinv[r]*y = dinv[r]^2*raw.
__global__ __launch_bounds__(256, 8) void k_spmm(
    const int* __restrict__ rowstart, const float* __restrict__ dinv,
    const unsigned int* __restrict__ ecv, const unsigned short* __restrict__ xin,
    unsigned short* __restrict__ bout) {
    int wv = (blockIdx.x * blockDim.x + threadIdx.x) >> 6;  // pair index
    if (wv >= NN / 2) return;
    int lane = threadIdx.x & 63;
    int h = lane >> 5, fp = lane & 31;
    int r = 2 * wv + h;
    int s = rowstart[r];
    int so = __shfl_xor(s, 32, 64);
    int m = h ? (s - so) : (so - s);     // common pair length
    float a0 = 0.f, a1 = 0.f;
    spmm_pair(ecv, s, m, xin, fp, a0, a1);
    float dv = dinv[r];
    float dv2 = dv * dv;
    a0 *= dv2; a1 *= dv2;
    unsigned int o = (unsigned int)f2bf(a0) | ((unsigned int)f2bf(a1) << 16);
    *(unsigned int*)(bout + r * DF + 2 * fp) = o;
}

// third SpMM with the output combine fused (y3 never hits memory);
// tables are prescaled by dinv[r], so y_k = table_k[r] * sqd[r].
__global__ __launch_bounds__(256, 8) void k_spmm_comb(
    const int* __restrict__ rowstart, const float* __restrict__ dinv,
    const float* __restrict__ sqd,
    const unsigned int* __restrict__ ecv, const unsigned short* __restrict__ xin,
    const float* __restrict__ x, const unsigned short* __restrict__ xb1,
    const float* __restrict__ gamma, float* __restrict__ out) {
    int wv = (blockIdx.x * blockDim.x + threadIdx.x) >> 6;
    if (wv >= NN / 2) return;
    int lane = threadIdx.x & 63;
    int h = lane >> 5, fp = lane & 31;
    int r = 2 * wv + h;
    int s = rowstart[r];
    int so = __shfl_xor(s, 32, 64);
    int m = h ? (s - so) : (so - s);
    float a0 = 0.f, a1 = 0.f;
    spmm_pair(ecv, s, m, xin, fp, a0, a1);
    float dv = dinv[r];
    a0 *= dv; a1 *= dv;                   // v3 pair (y3 = dinv*raw)
    float sq = sqd[r];
    int base = r * DF + 2 * fp;
    float2 v0 = *(const float2*)(x + base);
    unsigned int u1 = *(const unsigned int*)(xb1 + base);
    unsigned int u2 = *(const unsigned int*)(xin + base);   // xin == xs2 table
    float v1l = __uint_as_float(u1 << 16) * sq;
    float v1h = __uint_as_float(u1 & 0xFFFF0000u) * sq;
    float v2l = __uint_as_float(u2 << 16) * sq;
    float v2h = __uint_as_float(u2 & 0xFFFF0000u) * sq;
    float gm[OUT_K * OUT_K];
    #pragma unroll
    for (int t = 0; t < OUT_K * OUT_K; ++t) gm[t] = gamma[t];
    #pragma unroll
    for (int k = 0; k < OUT_K; ++k) {
        float2 o;
        o.x = gm[k * OUT_K + 0] * v0.x + gm[k * OUT_K + 1] * v1l +
              gm[k * OUT_K + 2] * v2l + gm[k * OUT_K + 3] * a0;
        o.y = gm[k * OUT_K + 0] * v0.y + gm[k * OUT_K + 1] * v1h +
              gm[k * OUT_K + 2] * v2h + gm[k * OUT_K + 3] * a1;
        *(float2*)(out + (r * OUT_K + k) * DF + 2 * fp) = o;
    }
}

// ---------------- launch ----------------

extern "C" void kernel_launch(void* const* d_in, const int* in_sizes, int n_in,
                              void* d_out, int out_size, void* d_ws, size_t ws_size,
                              hipStream_t stream) {
    const float* x      = (const float*)d_in[0];
    const int*   ei     = (const int*)d_in[1];
    const float* ea     = (const float*)d_in[2];
    const float* alphas = (const float*)d_in[3];
    const float* w      = (const float*)d_in[4];
    const float* a_arr  = (const float*)d_in[5];
    const float* b_arr  = (const float*)d_in[6];
    float* out = (float*)d_out;
    const int* row = ei;
    const int* col = ei + NE;

    char* ws = (char*)d_ws;
    size_t off = 0;
    auto alloc = [&](size_t bytes) {
        void* p = ws + off;
        off = (off + bytes + 255) & ~(size_t)255;
        return p;
    };
    // deg/counter then ecv are contiguous so ONE memset zeroes all
    // (ecv pad slots must be 0: col=0, bf16 weight=+0).
    int* deg      = (int*)alloc((size_t)(NN + 1) * sizeof(int));
    int* counter  = deg + NN;
    unsigned int* ecv = (unsigned int*)alloc((size_t)SLAB_CAP * sizeof(unsigned int));
    size_t zero_end = off;
    int* rowstart = (int*)alloc((size_t)NN * sizeof(int));
    float* dinv   = (float*)alloc((size_t)NN * sizeof(float));
    float* sqd    = (float*)alloc((size_t)NN * sizeof(float));
    unsigned short* rank = (unsigned short*)alloc((size_t)NE * sizeof(unsigned short));
    unsigned short* xb0 = (unsigned short*)alloc((size_t)NN * DF * sizeof(unsigned short));
    unsigned short* xb1 = (unsigned short*)alloc((size_t)NN * DF * sizeof(unsigned short));
    unsigned short* xb2 = (unsigned short*)alloc((size_t)NN * DF * sizeof(unsigned short));
    float* gamma = (float*)alloc((size_t)OUT_K * OUT_K * sizeof(float));

    (void)hipMemsetAsync(deg, 0, zero_end, stream);

    k_deg<<<(NE + 255) / 256, 256, 0, stream>>>(row, deg, rank);
    k_alloc<<<(NN + 1023) / 1024, 1024, 0, stream>>>(deg, counter, rowstart, dinv, sqd,
                                                     alphas, w, a_arr, b_arr, gamma);
    k_fill_cast<<<(NE + (NN * DF) / 8 + 255) / 256, 256, 0, stream>>>(
        row, col, ea, dinv, rowstart, rank, ecv, x, xb0);

    int blocks = (NN / 2 + 3) / 4;  // one wave per row PAIR, 4 pairs/block
    k_spmm<<<blocks, 256, 0, stream>>>(rowstart, dinv, ecv, xb0, xb1);
    k_spmm<<<blocks, 256, 0, stream>>>(rowstart, dinv, ecv, xb1, xb2);
    k_spmm_comb<<<blocks, 256, 0, stream>>>(rowstart, dinv, sqd, ecv, xb2, x, xb1,
                                            gamma, out);
}